// Round 4
// baseline (95.019 us; speedup 1.0000x reference)
//
#include <hip/hip_runtime.h>

// SkewedLossFunction_OneSide: mean(|y_pred - y_true| * exp(gate * |lam|))
//   lam  = y_true/50 - 1        (both reference branches collapse to this)
//   gate = 1 iff (y_true - y_pred) and lam have the same (nonzero) sign
//
// Two-pass reduce (fused single-accumulator atomics cost +52 us in round 2 —
// serialized cross-XCD atomic tail). Pass 1: 2048 blocks, each thread owns
// exactly 4 grid-stride float4 pairs, FULLY UNROLLED so all 8 loads are in
// flight before first use. Plain per-block partial store (no atomics).
// Pass 2: 1 block sums 2048 partials in double, writes mean.

#define N_ELEM   8388608
#define NBLOCKS  2048
#define NTHREADS 256

__device__ __forceinline__ float skew1(float p, float t) {
    float base = fabsf(p - t);
    float lam  = __fmaf_rn(t, 0.02f, -1.0f);     // y/50 - 1, in [-1, 1]
    // gate==1 iff sign(t-p)*sign(lam) > 0  <=>  (t-p)*lam > 0
    float g    = ((t - p) * lam > 0.0f) ? fabsf(lam) : 0.0f;
    return base * __expf(g);                     // exponent in [0,1]
}

__device__ __forceinline__ float skew4(float4 p, float4 t) {
    return skew1(p.x, t.x) + skew1(p.y, t.y) + skew1(p.z, t.z) + skew1(p.w, t.w);
}

__global__ __launch_bounds__(NTHREADS) void skew_partial_kernel(
        const float4* __restrict__ yp,
        const float4* __restrict__ yt,
        float* __restrict__ partial) {
    const int tid    = threadIdx.x;
    const int gid    = blockIdx.x * NTHREADS + tid;
    const int stride = NBLOCKS * NTHREADS;       // 524288; n4/stride == 4

    // Issue all 8 loads before any arithmetic: max MLP.
    float4 p0 = yp[gid];
    float4 t0 = yt[gid];
    float4 p1 = yp[gid + stride];
    float4 t1 = yt[gid + stride];
    float4 p2 = yp[gid + 2 * stride];
    float4 t2 = yt[gid + 2 * stride];
    float4 p3 = yp[gid + 3 * stride];
    float4 t3 = yt[gid + 3 * stride];

    float acc = skew4(p0, t0) + skew4(p1, t1) + skew4(p2, t2) + skew4(p3, t3);

    // wave-64 shuffle reduce
    #pragma unroll
    for (int off = 32; off > 0; off >>= 1)
        acc += __shfl_down(acc, off, 64);

    __shared__ float wsum[NTHREADS / 64];
    if ((tid & 63) == 0) wsum[tid >> 6] = acc;
    __syncthreads();
    if (tid == 0) {
        partial[blockIdx.x] = wsum[0] + wsum[1] + wsum[2] + wsum[3];
    }
}

__global__ __launch_bounds__(256) void skew_final_kernel(
        const float* __restrict__ partial,
        float* __restrict__ out) {
    const int tid = threadIdx.x;
    double acc = 0.0;
    #pragma unroll
    for (int i = tid; i < NBLOCKS; i += 256)
        acc += (double)partial[i];

    #pragma unroll
    for (int off = 32; off > 0; off >>= 1)
        acc += __shfl_down(acc, off, 64);

    __shared__ double wsum[256 / 64];
    if ((tid & 63) == 0) wsum[tid >> 6] = acc;
    __syncthreads();
    if (tid == 0) {
        double s = wsum[0] + wsum[1] + wsum[2] + wsum[3];
        out[0] = (float)(s / (double)N_ELEM);
    }
}

extern "C" void kernel_launch(void* const* d_in, const int* in_sizes, int n_in,
                              void* d_out, int out_size, void* d_ws, size_t ws_size,
                              hipStream_t stream) {
    const float4* y_pred = (const float4*)d_in[0];
    const float4* y_true = (const float4*)d_in[1];
    float* partial = (float*)d_ws;          // NBLOCKS * 4 B = 8 KiB
    float* out     = (float*)d_out;

    skew_partial_kernel<<<NBLOCKS, NTHREADS, 0, stream>>>(y_pred, y_true, partial);
    skew_final_kernel<<<1, 256, 0, stream>>>(partial, out);
}